// Round 11
// baseline (49.022 us; speedup 1.0000x reference)
//
#include <hip/hip_runtime.h>
#include <math.h>

#define NB     8
#define NPTS   32768
#define KPRIM  128
#define NSKEL  2048
#define NCTRL  4
#define NT     16
#define NCURVE (KPRIM * NT)          // 2048 curve points per batch
#define TOTAL_OCC (NB * NPTS)        // 262144 rows (B*Np)

// workspace layout (in floats) — no atomics, all per-block partials
#define WS_MINA   0                               // [b][n][8] chunk minima
#define WS_MINB   (WS_MINA + NB * NSKEL * 8)      // [b][m][8]
#define WS_OVP    (WS_MINB + NB * NCURVE * 8)     // overlap partials [4096]
#define WS_RCP    (WS_OVP + 4096)                 // recon partials [256]

#define NBLK_CHA  512
#define NBLK_CHB  512
#define NBLK_RC   256
#define NBLK_OV   4096
#define RC_BASE   (NBLK_CHA + NBLK_CHB)           // 1024
#define NBLK_ALL  5376                            // 21 * 256

// Interleaved dispatch: 256 groups of 21 blocks = 5 compute + 16 overlap.
// Compute:overlap = 1280:4096 = 5:16 exactly, so initial CU residency is
// ~76% streaming blocks instead of 0% (compute-first) — BW ramps immediately.
__global__ void mega_kernel(const float4* __restrict__ occ,
                            const float4* __restrict__ pred,
                            const float4* __restrict__ gt,
                            const float* __restrict__ skel,
                            const float* __restrict__ prim,
                            const float* __restrict__ w,
                            const float* __restrict__ basis,
                            float* __restrict__ minA,
                            float* __restrict__ minB,
                            float* __restrict__ ovp,
                            float* __restrict__ rcp) {
    int raw  = blockIdx.x;
    int gi   = raw / 21;
    int slot = raw - gi * 21;
    int t    = threadIdx.x;
    __shared__ float4 tile[256];
    float* sred = (float*)tile;

    if (slot >= 5) {
        // ---- overlap: 64 rows/block; thread owns 1/4 row (128 B contiguous)
        int bid2 = gi * 16 + (slot - 5);   // 0..4095
        int g = t >> 2;                    // row within block
        int j = t & 3;                     // quarter within row
        const float4* src = occ + (size_t)bid2 * 2048 + g * 32 + j * 8;
        float4 v0 = src[0];
        float4 v1 = src[1];
        float4 v2 = src[2];
        float4 v3 = src[3];
        float4 v4 = src[4];
        float4 v5 = src[5];
        float4 v6 = src[6];
        float4 v7 = src[7];
        float s;
        {
            float s0 = (v0.x > 0.5f ? v0.x : 0.0f) + (v0.y > 0.5f ? v0.y : 0.0f)
                     + (v0.z > 0.5f ? v0.z : 0.0f) + (v0.w > 0.5f ? v0.w : 0.0f);
            float s1 = (v1.x > 0.5f ? v1.x : 0.0f) + (v1.y > 0.5f ? v1.y : 0.0f)
                     + (v1.z > 0.5f ? v1.z : 0.0f) + (v1.w > 0.5f ? v1.w : 0.0f);
            float s2 = (v2.x > 0.5f ? v2.x : 0.0f) + (v2.y > 0.5f ? v2.y : 0.0f)
                     + (v2.z > 0.5f ? v2.z : 0.0f) + (v2.w > 0.5f ? v2.w : 0.0f);
            float s3 = (v3.x > 0.5f ? v3.x : 0.0f) + (v3.y > 0.5f ? v3.y : 0.0f)
                     + (v3.z > 0.5f ? v3.z : 0.0f) + (v3.w > 0.5f ? v3.w : 0.0f);
            float s4 = (v4.x > 0.5f ? v4.x : 0.0f) + (v4.y > 0.5f ? v4.y : 0.0f)
                     + (v4.z > 0.5f ? v4.z : 0.0f) + (v4.w > 0.5f ? v4.w : 0.0f);
            float s5 = (v5.x > 0.5f ? v5.x : 0.0f) + (v5.y > 0.5f ? v5.y : 0.0f)
                     + (v5.z > 0.5f ? v5.z : 0.0f) + (v5.w > 0.5f ? v5.w : 0.0f);
            float s6 = (v6.x > 0.5f ? v6.x : 0.0f) + (v6.y > 0.5f ? v6.y : 0.0f)
                     + (v6.z > 0.5f ? v6.z : 0.0f) + (v6.w > 0.5f ? v6.w : 0.0f);
            float s7 = (v7.x > 0.5f ? v7.x : 0.0f) + (v7.y > 0.5f ? v7.y : 0.0f)
                     + (v7.z > 0.5f ? v7.z : 0.0f) + (v7.w > 0.5f ? v7.w : 0.0f);
            s = ((s0 + s1) + (s2 + s3)) + ((s4 + s5) + (s6 + s7));
        }
        s += __shfl_xor(s, 1);
        s += __shfl_xor(s, 2);             // all 4 lanes of group hold rowsum
        if (j == 0) sred[g] = fmaxf(s - 32.0f, 0.0f);
        __syncthreads();
        if (t < 64) {                      // one wave reduces 64 row penalties
            float p = sred[t];
            p += __shfl_xor(p, 1);
            p += __shfl_xor(p, 2);
            p += __shfl_xor(p, 4);
            p += __shfl_xor(p, 8);
            p += __shfl_xor(p, 16);
            p += __shfl_xor(p, 32);
            if (t == 0) ovp[bid2] = p;
        }
        return;
    }

    int cid = gi * 5 + slot;               // 0..1279
    if (cid < NBLK_CHA) {
        // ---- chamfer A: per skeleton point, min over 256 inline curve pts --
        int b  = cid >> 6;
        int rm = cid & 63;
        int nb = rm >> 3;      // skel chunk (8 x 256)
        int mc = rm & 7;       // curve chunk (8 x 256)
        {
            int k  = mc * 16 + (t >> 4);
            int tt = t & 15;
            int bk = b * KPRIM + k;
            float ww = w[bk];
            const float* p  = prim + bk * 16;
            const float* bs = basis + tt * 4;
            float x = ww * (bs[0] * p[0] + bs[1] * p[3] + bs[2] * p[6] + bs[3] * p[9]);
            float y = ww * (bs[0] * p[1] + bs[1] * p[4] + bs[2] * p[7] + bs[3] * p[10]);
            float z = ww * (bs[0] * p[2] + bs[1] * p[5] + bs[2] * p[8] + bs[3] * p[11]);
            tile[t] = make_float4(x, y, z, 0.0f);
        }
        __syncthreads();

        int n = nb * 256 + t;
        const float* s = skel + ((size_t)b * NSKEL + n) * 3;
        float ax = s[0], ay = s[1], az = s[2];

        float m0 = 3.4e38f, m1 = 3.4e38f, m2 = 3.4e38f, m3 = 3.4e38f;
        for (int m = 0; m < 256; m += 4) {
            float4 c0 = tile[m], c1 = tile[m + 1], c2 = tile[m + 2], c3 = tile[m + 3];
            float dx, dy, dz;
            dx = ax - c0.x; dy = ay - c0.y; dz = az - c0.z;
            m0 = fminf(m0, fmaf(dz, dz, fmaf(dy, dy, dx * dx)));
            dx = ax - c1.x; dy = ay - c1.y; dz = az - c1.z;
            m1 = fminf(m1, fmaf(dz, dz, fmaf(dy, dy, dx * dx)));
            dx = ax - c2.x; dy = ay - c2.y; dz = az - c2.z;
            m2 = fminf(m2, fmaf(dz, dz, fmaf(dy, dy, dx * dx)));
            dx = ax - c3.x; dy = ay - c3.y; dz = az - c3.z;
            m3 = fminf(m3, fmaf(dz, dz, fmaf(dy, dy, dx * dx)));
        }
        float md = fminf(fminf(m0, m1), fminf(m2, m3));
        minA[((size_t)b * NSKEL + n) * 8 + mc] = md;
    } else if (cid < RC_BASE) {
        // ---- chamfer B: per inline curve point, min over 256 skel pts ----
        int bx2 = cid - NBLK_CHA;
        int b  = bx2 >> 6;
        int rm = bx2 & 63;
        int mb = rm >> 3;      // curve-point chunk (8 x 256)
        int nc = rm & 7;       // skel chunk (8 x 256)
        float* sf = (float*)tile;
        const float* ssrc = skel + (size_t)b * NSKEL * 3 + (size_t)nc * 256 * 3;
        for (int i = t; i < 768; i += 256) {
            int p = i / 3, c = i % 3;
            sf[p * 4 + c] = ssrc[i];
        }
        __syncthreads();

        int m  = mb * 256 + t;
        float ax, ay, az;
        {
            int k  = m >> 4;
            int tt = m & 15;
            int bk = b * KPRIM + k;
            float ww = w[bk];
            const float* p  = prim + bk * 16;
            const float* bs = basis + tt * 4;
            ax = ww * (bs[0] * p[0] + bs[1] * p[3] + bs[2] * p[6] + bs[3] * p[9]);
            ay = ww * (bs[0] * p[1] + bs[1] * p[4] + bs[2] * p[7] + bs[3] * p[10]);
            az = ww * (bs[0] * p[2] + bs[1] * p[5] + bs[2] * p[8] + bs[3] * p[11]);
        }

        float m0 = 3.4e38f, m1 = 3.4e38f, m2 = 3.4e38f, m3 = 3.4e38f;
        for (int n = 0; n < 256; n += 4) {
            float4 c0 = tile[n], c1 = tile[n + 1], c2 = tile[n + 2], c3 = tile[n + 3];
            float dx, dy, dz;
            dx = ax - c0.x; dy = ay - c0.y; dz = az - c0.z;
            m0 = fminf(m0, fmaf(dz, dz, fmaf(dy, dy, dx * dx)));
            dx = ax - c1.x; dy = ay - c1.y; dz = az - c1.z;
            m1 = fminf(m1, fmaf(dz, dz, fmaf(dy, dy, dx * dx)));
            dx = ax - c2.x; dy = ay - c2.y; dz = az - c2.z;
            m2 = fminf(m2, fmaf(dz, dz, fmaf(dy, dy, dx * dx)));
            dx = ax - c3.x; dy = ay - c3.y; dz = az - c3.z;
            m3 = fminf(m3, fmaf(dz, dz, fmaf(dy, dy, dx * dx)));
        }
        float md = fminf(fminf(m0, m1), fminf(m2, m3));
        minB[((size_t)b * NCURVE + m) * 8 + nc] = md;
    } else {
        // ---- recon: mean((pred-gt)^2) partials ----
        int bid2 = cid - RC_BASE;
        int idx = bid2 * 256 + t;          // over TOTAL_OCC/4 = 65536
        float4 p = pred[idx];
        float4 g = gt[idx];
        float dx = p.x - g.x, dy = p.y - g.y, dz = p.z - g.z, dw = p.w - g.w;
        float s = dx * dx + dy * dy + dz * dz + dw * dw;
        s += __shfl_xor(s, 1);
        s += __shfl_xor(s, 2);
        s += __shfl_xor(s, 4);
        s += __shfl_xor(s, 8);
        s += __shfl_xor(s, 16);
        s += __shfl_xor(s, 32);
        if ((t & 63) == 0) sred[t >> 6] = s;
        __syncthreads();
        if (t == 0) rcp[bid2] = sred[0] + sred[1] + sred[2] + sred[3];
    }
}

// ---------------- finalize: one block per batch, vectorized loads ----------
__device__ inline float blk_reduce(float v, float* red) {
    int t = threadIdx.x;
    __syncthreads();
    red[t] = v; __syncthreads();
    for (int st = 128; st > 0; st >>= 1) {
        if (t < st) red[t] += red[t + st];
        __syncthreads();
    }
    return red[0];
}

__device__ inline float min8(float4 u, float4 v) {
    return fminf(fminf(fminf(u.x, u.y), fminf(u.z, u.w)),
                 fminf(fminf(v.x, v.y), fminf(v.z, v.w)));
}

__global__ void finalize_kernel(const float* __restrict__ wts,
                                const float* __restrict__ minA,
                                const float* __restrict__ minB,
                                const float* __restrict__ ovp,
                                const float* __restrict__ rcp,
                                float* __restrict__ out) {
    int b = blockIdx.x;
    int t = threadIdx.x;
    float ca = 0.0f, cb = 0.0f, ps = 0.0f, ov = 0.0f, rc;

    const float4* qa = (const float4*)(minA + (size_t)b * NSKEL * 8);
#pragma unroll
    for (int i = t; i < NSKEL; i += 256)          // 8 independent iterations
        ca += sqrtf(min8(qa[2 * i], qa[2 * i + 1]));

    const float4* qb = (const float4*)(minB + (size_t)b * NCURVE * 8);
#pragma unroll
    for (int i = t; i < NCURVE; i += 256)         // 8 independent iterations
        cb += sqrtf(min8(qb[2 * i], qb[2 * i + 1]));

#pragma unroll
    for (int i = t; i < NB * KPRIM; i += 256) {   // 4 iterations
        float x = wts[i];
        ps += 1.0f / (1.0f + expf(-x));
    }

    const float4* ov4 = (const float4*)ovp;
#pragma unroll
    for (int i = t; i < NBLK_OV / 4; i += 256) {  // 4 iterations of float4
        float4 v = ov4[i];
        ov += v.x + v.y + v.z + v.w;
    }
    rc = rcp[t];

    __shared__ float red[256];
    float ca_s = blk_reduce(ca, red);
    float cb_s = blk_reduce(cb, red);
    float ps_s = blk_reduce(ps, red);
    float ov_s = blk_reduce(ov, red);
    float rc_s = blk_reduce(rc, red);
    if (t == 0) {
        float recon = rc_s / (float)TOTAL_OCC;
        float overl = 0.1f * ov_s / (float)TOTAL_OCC;
        float pars  = 0.1f * sqrtf(ps_s);
        out[b] = recon + overl + pars + ca_s / (float)NSKEL + cb_s / (float)NCURVE;
    }
}

extern "C" void kernel_launch(void* const* d_in, const int* in_sizes, int n_in,
                              void* d_out, int out_size, void* d_ws, size_t ws_size,
                              hipStream_t stream) {
    const float* pred  = (const float*)d_in[0];
    const float* gt    = (const float*)d_in[1];
    const float* occ   = (const float*)d_in[2];
    const float* prim  = (const float*)d_in[3];
    const float* wts   = (const float*)d_in[4];
    const float* skel  = (const float*)d_in[5];
    const float* basis = (const float*)d_in[6];
    float* out = (float*)d_out;
    float* ws  = (float*)d_ws;

    float* minA = ws + WS_MINA;
    float* minB = ws + WS_MINB;
    float* ovp  = ws + WS_OVP;
    float* rcp  = ws + WS_RCP;

    mega_kernel<<<NBLK_ALL, 256, 0, stream>>>(
        (const float4*)occ, (const float4*)pred, (const float4*)gt,
        skel, prim, wts, basis, minA, minB, ovp, rcp);
    finalize_kernel<<<NB, 256, 0, stream>>>(wts, minA, minB, ovp, rcp, out);
}

// Round 13
// 39.550 us; speedup vs baseline: 1.2395x; 1.2395x over previous
//
#include <hip/hip_runtime.h>
#include <math.h>

#define NB     8
#define NPTS   32768
#define KPRIM  128
#define NSKEL  2048
#define NCTRL  4
#define NT     16
#define NCURVE (KPRIM * NT)          // 2048 curve points per batch
#define TOTAL_OCC (NB * NPTS)        // 262144 rows (B*Np)

// workspace layout (in floats) — no atomics, all per-block partials
#define WS_MINA   0                               // [b][n][8] chunk minima
#define WS_MINB   (WS_MINA + NB * NSKEL * 8)      // [b][m][8]
#define WS_OVP    (WS_MINB + NB * NCURVE * 8)     // overlap partials [2048]
#define WS_RCP    (WS_OVP + 2048)                 // recon partials [256]

#define NBLK_CHA  512
#define NBLK_CHB  512
#define NBLK_RC   256
#define NBLK_OV   2048                            // 128 rows per block now
#define RC_BASE   (NBLK_CHA + NBLK_CHB)           // 1024
#define OV_BASE   (RC_BASE + NBLK_RC)             // 1280
#define NBLK_ALL  (OV_BASE + NBLK_OV)             // 3328

__device__ inline float msum4(float4 v) {
    return (v.x > 0.5f ? v.x : 0.0f) + (v.y > 0.5f ? v.y : 0.0f) +
           (v.z > 0.5f ? v.z : 0.0f) + (v.w > 0.5f ? v.w : 0.0f);
}

// mega: chamferA | chamferB | recon | overlap (compute first — R10 ordering)
__global__ void mega_kernel(const float4* __restrict__ occ,
                            const float4* __restrict__ pred,
                            const float4* __restrict__ gt,
                            const float* __restrict__ skel,
                            const float* __restrict__ prim,
                            const float* __restrict__ w,
                            const float* __restrict__ basis,
                            float* __restrict__ minA,
                            float* __restrict__ minB,
                            float* __restrict__ ovp,
                            float* __restrict__ rcp) {
    int bid = blockIdx.x;
    int t   = threadIdx.x;
    __shared__ float4 tile[256];
    float* sred = (float*)tile;

    if (bid < NBLK_CHA) {
        // ---- chamfer A: per skeleton point, min over 256 inline curve pts --
        int b  = bid >> 6;
        int rm = bid & 63;
        int nb = rm >> 3;      // skel chunk (8 x 256)
        int mc = rm & 7;       // curve chunk (8 x 256)
        {
            int k  = mc * 16 + (t >> 4);
            int tt = t & 15;
            int bk = b * KPRIM + k;
            float ww = w[bk];
            const float* p  = prim + bk * 16;
            const float* bs = basis + tt * 4;
            float x = ww * (bs[0] * p[0] + bs[1] * p[3] + bs[2] * p[6] + bs[3] * p[9]);
            float y = ww * (bs[0] * p[1] + bs[1] * p[4] + bs[2] * p[7] + bs[3] * p[10]);
            float z = ww * (bs[0] * p[2] + bs[1] * p[5] + bs[2] * p[8] + bs[3] * p[11]);
            tile[t] = make_float4(x, y, z, 0.0f);
        }
        __syncthreads();

        int n = nb * 256 + t;
        const float* s = skel + ((size_t)b * NSKEL + n) * 3;
        float ax = s[0], ay = s[1], az = s[2];

        float m0 = 3.4e38f, m1 = 3.4e38f, m2 = 3.4e38f, m3 = 3.4e38f;
        for (int m = 0; m < 256; m += 4) {
            float4 c0 = tile[m], c1 = tile[m + 1], c2 = tile[m + 2], c3 = tile[m + 3];
            float dx, dy, dz;
            dx = ax - c0.x; dy = ay - c0.y; dz = az - c0.z;
            m0 = fminf(m0, fmaf(dz, dz, fmaf(dy, dy, dx * dx)));
            dx = ax - c1.x; dy = ay - c1.y; dz = az - c1.z;
            m1 = fminf(m1, fmaf(dz, dz, fmaf(dy, dy, dx * dx)));
            dx = ax - c2.x; dy = ay - c2.y; dz = az - c2.z;
            m2 = fminf(m2, fmaf(dz, dz, fmaf(dy, dy, dx * dx)));
            dx = ax - c3.x; dy = ay - c3.y; dz = az - c3.z;
            m3 = fminf(m3, fmaf(dz, dz, fmaf(dy, dy, dx * dx)));
        }
        float md = fminf(fminf(m0, m1), fminf(m2, m3));
        minA[((size_t)b * NSKEL + n) * 8 + mc] = md;
    } else if (bid < RC_BASE) {
        // ---- chamfer B: per inline curve point, min over 256 skel pts ----
        int bx2 = bid - NBLK_CHA;
        int b  = bx2 >> 6;
        int rm = bx2 & 63;
        int mb = rm >> 3;      // curve-point chunk (8 x 256)
        int nc = rm & 7;       // skel chunk (8 x 256)
        float* sf = (float*)tile;
        const float* ssrc = skel + (size_t)b * NSKEL * 3 + (size_t)nc * 256 * 3;
        for (int i = t; i < 768; i += 256) {
            int p = i / 3, c = i % 3;
            sf[p * 4 + c] = ssrc[i];
        }
        __syncthreads();

        int m  = mb * 256 + t;
        float ax, ay, az;
        {
            int k  = m >> 4;
            int tt = m & 15;
            int bk = b * KPRIM + k;
            float ww = w[bk];
            const float* p  = prim + bk * 16;
            const float* bs = basis + tt * 4;
            ax = ww * (bs[0] * p[0] + bs[1] * p[3] + bs[2] * p[6] + bs[3] * p[9]);
            ay = ww * (bs[0] * p[1] + bs[1] * p[4] + bs[2] * p[7] + bs[3] * p[10]);
            az = ww * (bs[0] * p[2] + bs[1] * p[5] + bs[2] * p[8] + bs[3] * p[11]);
        }

        float m0 = 3.4e38f, m1 = 3.4e38f, m2 = 3.4e38f, m3 = 3.4e38f;
        for (int n = 0; n < 256; n += 4) {
            float4 c0 = tile[n], c1 = tile[n + 1], c2 = tile[n + 2], c3 = tile[n + 3];
            float dx, dy, dz;
            dx = ax - c0.x; dy = ay - c0.y; dz = az - c0.z;
            m0 = fminf(m0, fmaf(dz, dz, fmaf(dy, dy, dx * dx)));
            dx = ax - c1.x; dy = ay - c1.y; dz = az - c1.z;
            m1 = fminf(m1, fmaf(dz, dz, fmaf(dy, dy, dx * dx)));
            dx = ax - c2.x; dy = ay - c2.y; dz = az - c2.z;
            m2 = fminf(m2, fmaf(dz, dz, fmaf(dy, dy, dx * dx)));
            dx = ax - c3.x; dy = ay - c3.y; dz = az - c3.z;
            m3 = fminf(m3, fmaf(dz, dz, fmaf(dy, dy, dx * dx)));
        }
        float md = fminf(fminf(m0, m1), fminf(m2, m3));
        minB[((size_t)b * NCURVE + m) * 8 + nc] = md;
    } else if (bid < OV_BASE) {
        // ---- recon: mean((pred-gt)^2) partials ----
        int bid2 = bid - RC_BASE;
        int idx = bid2 * 256 + t;          // over TOTAL_OCC/4 = 65536
        float4 p = pred[idx];
        float4 g = gt[idx];
        float dx = p.x - g.x, dy = p.y - g.y, dz = p.z - g.z, dw = p.w - g.w;
        float s = dx * dx + dy * dy + dz * dz + dw * dw;
        s += __shfl_xor(s, 1);
        s += __shfl_xor(s, 2);
        s += __shfl_xor(s, 4);
        s += __shfl_xor(s, 8);
        s += __shfl_xor(s, 16);
        s += __shfl_xor(s, 32);
        if ((t & 63) == 0) sred[t >> 6] = s;
        __syncthreads();
        if (t == 0) rcp[bid2] = sred[0] + sred[1] + sred[2] + sred[3];
    } else {
        // ---- overlap: 128 rows/block, 16 loads/thread issued back-to-back
        // thread covers quarter-rows of row g and row g+64 (256 B total).
        int bid2 = bid - OV_BASE;          // 0..2047
        int g = t >> 2;                    // row 0..63
        int j = t & 3;                     // quarter within row
        const float4* src  = occ + (size_t)bid2 * 4096 + g * 32 + j * 8;
        const float4* src2 = src + 2048;   // row g+64
        // all 16 loads issued before any use — 256 B in flight per thread
        float4 v0 = src[0],  v1 = src[1],  v2 = src[2],  v3 = src[3];
        float4 v4 = src[4],  v5 = src[5],  v6 = src[6],  v7 = src[7];
        float4 u0 = src2[0], u1 = src2[1], u2 = src2[2], u3 = src2[3];
        float4 u4 = src2[4], u5 = src2[5], u6 = src2[6], u7 = src2[7];

        float s = ((msum4(v0) + msum4(v1)) + (msum4(v2) + msum4(v3))) +
                  ((msum4(v4) + msum4(v5)) + (msum4(v6) + msum4(v7)));
        float r = ((msum4(u0) + msum4(u1)) + (msum4(u2) + msum4(u3))) +
                  ((msum4(u4) + msum4(u5)) + (msum4(u6) + msum4(u7)));
        s += __shfl_xor(s, 1);
        s += __shfl_xor(s, 2);
        r += __shfl_xor(r, 1);
        r += __shfl_xor(r, 2);
        if (j == 0) {
            sred[g]      = fmaxf(s - 32.0f, 0.0f);
            sred[g + 64] = fmaxf(r - 32.0f, 0.0f);
        }
        __syncthreads();
        if (t < 128) {                     // 2 waves reduce 128 penalties
            float p = sred[t];
            p += __shfl_xor(p, 1);
            p += __shfl_xor(p, 2);
            p += __shfl_xor(p, 4);
            p += __shfl_xor(p, 8);
            p += __shfl_xor(p, 16);
            p += __shfl_xor(p, 32);
            if ((t & 63) == 0) sred[128 + (t >> 6)] = p;
        }
        __syncthreads();
        if (t == 0) ovp[bid2] = sred[128] + sred[129];
    }
}

// ---------------- finalize: one block per batch, vectorized loads ----------
__device__ inline float blk_reduce(float v, float* red) {
    int t = threadIdx.x;
    __syncthreads();
    red[t] = v; __syncthreads();
    for (int st = 128; st > 0; st >>= 1) {
        if (t < st) red[t] += red[t + st];
        __syncthreads();
    }
    return red[0];
}

__device__ inline float min8(float4 u, float4 v) {
    return fminf(fminf(fminf(u.x, u.y), fminf(u.z, u.w)),
                 fminf(fminf(v.x, v.y), fminf(v.z, v.w)));
}

__global__ void finalize_kernel(const float* __restrict__ wts,
                                const float* __restrict__ minA,
                                const float* __restrict__ minB,
                                const float* __restrict__ ovp,
                                const float* __restrict__ rcp,
                                float* __restrict__ out) {
    int b = blockIdx.x;
    int t = threadIdx.x;
    float ca = 0.0f, cb = 0.0f, ps = 0.0f, ov = 0.0f, rc;

    const float4* qa = (const float4*)(minA + (size_t)b * NSKEL * 8);
#pragma unroll
    for (int i = t; i < NSKEL; i += 256)          // 8 independent iterations
        ca += sqrtf(min8(qa[2 * i], qa[2 * i + 1]));

    const float4* qb = (const float4*)(minB + (size_t)b * NCURVE * 8);
#pragma unroll
    for (int i = t; i < NCURVE; i += 256)         // 8 independent iterations
        cb += sqrtf(min8(qb[2 * i], qb[2 * i + 1]));

#pragma unroll
    for (int i = t; i < NB * KPRIM; i += 256) {   // 4 iterations
        float x = wts[i];
        ps += 1.0f / (1.0f + expf(-x));
    }

    const float4* ov4 = (const float4*)ovp;
#pragma unroll
    for (int i = t; i < NBLK_OV / 4; i += 256) {  // 2 iterations of float4
        float4 v = ov4[i];
        ov += v.x + v.y + v.z + v.w;
    }
    rc = rcp[t];

    __shared__ float red[256];
    float ca_s = blk_reduce(ca, red);
    float cb_s = blk_reduce(cb, red);
    float ps_s = blk_reduce(ps, red);
    float ov_s = blk_reduce(ov, red);
    float rc_s = blk_reduce(rc, red);
    if (t == 0) {
        float recon = rc_s / (float)TOTAL_OCC;
        float overl = 0.1f * ov_s / (float)TOTAL_OCC;
        float pars  = 0.1f * sqrtf(ps_s);
        out[b] = recon + overl + pars + ca_s / (float)NSKEL + cb_s / (float)NCURVE;
    }
}

extern "C" void kernel_launch(void* const* d_in, const int* in_sizes, int n_in,
                              void* d_out, int out_size, void* d_ws, size_t ws_size,
                              hipStream_t stream) {
    const float* pred  = (const float*)d_in[0];
    const float* gt    = (const float*)d_in[1];
    const float* occ   = (const float*)d_in[2];
    const float* prim  = (const float*)d_in[3];
    const float* wts   = (const float*)d_in[4];
    const float* skel  = (const float*)d_in[5];
    const float* basis = (const float*)d_in[6];
    float* out = (float*)d_out;
    float* ws  = (float*)d_ws;

    float* minA = ws + WS_MINA;
    float* minB = ws + WS_MINB;
    float* ovp  = ws + WS_OVP;
    float* rcp  = ws + WS_RCP;

    mega_kernel<<<NBLK_ALL, 256, 0, stream>>>(
        (const float4*)occ, (const float4*)pred, (const float4*)gt,
        skel, prim, wts, basis, minA, minB, ovp, rcp);
    finalize_kernel<<<NB, 256, 0, stream>>>(wts, minA, minB, ovp, rcp, out);
}